// Round 8
// baseline (500.411 us; speedup 1.0000x reference)
//
#include <hip/hip_runtime.h>
#include <stdint.h>

// Problem constants
#define B_   4
#define P_   20000
#define NB_  9
#define WN_  17
#define CI_  64
#define CO_  128
#define PTS  16            // points per block -> 64 rows = 2 M-tiles of 32
#define NBLK (P_ / PTS)    // 1250 blocks

typedef __fp16 f16x8 __attribute__((ext_vector_type(8)));
typedef __fp16 h2    __attribute__((ext_vector_type(2)));
typedef float  f32x16 __attribute__((ext_vector_type(16)));

union H2U { h2 h; uint32_t u; };
union F8U { f16x8 v; h2 h[4]; uint4 u; };

// wsb granule (16B = 8 f16): index ((m*8 + oct)*128 + co)*8 ushorts.
// Consecutive co contiguous -> a wave's 32-lane fragment load is 512B dense.
__global__ void prep_wm(const float* __restrict__ w, ushort* __restrict__ wsb) {
    int i = blockIdx.x * 256 + threadIdx.x;     // 0 .. 17407 (17*8*128)
    int m   = i >> 10;                          // 1024 granules per m
    int r   = i & 1023;
    int oct = r >> 7, co = r & 127;
    const float* src = w + (size_t)m * (CO_ * CI_) + co * CI_ + oct * 8;
    float4 v0 = *(const float4*)(src);
    float4 v1 = *(const float4*)(src + 4);
    F8U h;
    h.h[0] = __builtin_amdgcn_cvt_pkrtz(v0.x, v0.y);
    h.h[1] = __builtin_amdgcn_cvt_pkrtz(v0.z, v0.w);
    h.h[2] = __builtin_amdgcn_cvt_pkrtz(v1.x, v1.y);
    h.h[3] = __builtin_amdgcn_cvt_pkrtz(v1.z, v1.w);
    *(uint4*)&wsb[(size_t)((m * 8 + oct) * 128 + co) * 8] = h.u;
}

template <bool PRE>
__global__ __launch_bounds__(256, 4)
void lasm_fused(const float* __restrict__ in_pc,    // (B,P,CI)    f32
                const float* __restrict__ raw_w,    // (P,NB,WN)   f32
                const float* __restrict__ weights,  // (WN,CO*CI)  f32
                const float* __restrict__ bias,     // (P,CO)      f32
                const int*   __restrict__ nbr,      // (P,NB)      int32
                const ushort* __restrict__ wsb,     // pre-swizzled f16 panel
                float*       __restrict__ out)      // (B,P,CO)    f32
{
    __shared__ __align__(16) int      s_nid[PTS * NB_];      // 144 ints
    __shared__ __align__(16) uint32_t s_w2[WN_ * NB_ * 17];  // [(m*9+n)*17+pl], ~10.4 KB

    const int tid  = threadIdx.x;
    const int lane = tid & 63;
    const int wv   = tid >> 6;
    const int arow = lane & 31;       // row within M-tile / co within co-tile
    const int q    = lane >> 5;       // k-half
    const int mt   = wv >> 1;         // M-tile: rows mt*32 .. mt*32+31
    const int ch   = wv & 1;          // co half: cols ch*64 .. ch*64+63
    const int p0   = blockIdx.x * PTS;

    // ---- prologue staging (the ONLY barrier in the kernel) ----
    if (tid < PTS * NB_) s_nid[tid] = nbr[p0 * NB_ + tid];
    for (int idx = tid; idx < PTS * NB_ * WN_; idx += 256) {
        int pl2 = idx / (NB_ * WN_);
        int rem = idx % (NB_ * WN_);
        int n   = rem / WN_;
        int m   = rem % WN_;
        float wf = raw_w[(size_t)p0 * NB_ * WN_ + idx];
        H2U c; c.h = __builtin_amdgcn_cvt_pkrtz(wf, wf);
        s_w2[(m * NB_ + n) * 17 + pl2] = c.u;
    }
    __syncthreads();

    f32x16 acc[2];
    #pragma unroll
    for (int c = 0; c < 2; ++c)
        #pragma unroll
        for (int j = 0; j < 16; ++j) acc[c][j] = 0.f;

    const int brow = mt * 2 + (arow >> 4);    // batch of this lane's row
    const int pl   = arow & 15;               // point-local index
    const size_t binpc = (size_t)brow * P_ * CI_;
    const int oct = /* this lane-half's k-oct per pass: */ q;  // + 2*pass at use

    // B-fragment: direct global->VGPR (L2-resident panel, no LDS, no barrier)
    auto load_b = [&](int m, int pass, int c) -> f16x8 {
        int o = 2 * pass + q;
        if (PRE) {
            F8U r;
            r.u = *(const uint4*)&wsb[(size_t)((m * 8 + o) * 128
                                               + ch * 64 + c * 32 + arow) * 8];
            return r.v;
        } else {
            const float* s = weights + (size_t)m * (CO_ * CI_)
                           + (ch * 64 + c * 32 + arow) * CI_ + o * 8;
            float4 v0 = *(const float4*)(s);
            float4 v1 = *(const float4*)(s + 4);
            F8U r;
            r.h[0] = __builtin_amdgcn_cvt_pkrtz(v0.x, v0.y);
            r.h[1] = __builtin_amdgcn_cvt_pkrtz(v0.z, v0.w);
            r.h[2] = __builtin_amdgcn_cvt_pkrtz(v1.x, v1.y);
            r.h[3] = __builtin_amdgcn_cvt_pkrtz(v1.z, v1.w);
            return r.v;
        }
    };

    #pragma unroll 1
    for (int pass = 0; pass < 4; ++pass) {
        // ---- gather x for this pass's single k-oct (2*pass+q), 32B/neighbor ----
        h2 x[NB_][4];
        const int ch0 = (2 * pass + q) * 8;
        #pragma unroll
        for (int n = 0; n < NB_; ++n) {
            uint32_t nid = (uint32_t)s_nid[pl * NB_ + n];
            if (nid < (uint32_t)P_) {
                const float* src = in_pc + binpc + (size_t)nid * CI_ + ch0;
                float4 a0 = *(const float4*)(src);
                float4 a1 = *(const float4*)(src + 4);
                x[n][0] = __builtin_amdgcn_cvt_pkrtz(a0.x, a0.y);
                x[n][1] = __builtin_amdgcn_cvt_pkrtz(a0.z, a0.w);
                x[n][2] = __builtin_amdgcn_cvt_pkrtz(a1.x, a1.y);
                x[n][3] = __builtin_amdgcn_cvt_pkrtz(a1.z, a1.w);
            } else {
                h2 z = {(__fp16)0.f, (__fp16)0.f};
                x[n][0] = z; x[n][1] = z; x[n][2] = z; x[n][3] = z;
            }
        }

        // ---- software-pipelined, barrier-free m-loop (one k16 chunk per m) ----
        f16x8 bC0 = load_b(0, pass, 0);
        f16x8 bC1 = load_b(0, pass, 1);

        for (int m = 0; m < WN_; ++m) {
            // per-lane w for its point
            H2U wc[9];
            #pragma unroll
            for (int n = 0; n < NB_; ++n) wc[n].u = s_w2[(m * NB_ + n) * 17 + pl];

            // stage-1 in registers: fuse[row=arow][oct 2*pass+q] (8 f16)
            F8U f;
            #pragma unroll
            for (int r4 = 0; r4 < 4; ++r4) {
                h2 c = {(__fp16)0.f, (__fp16)0.f};
                #pragma unroll
                for (int n = 0; n < NB_; ++n) c += wc[n].h * x[n][r4];
                f.h[r4] = c;
            }

            int mn = (m + 1 < WN_) ? m + 1 : m;       // clamped prefetch
            f16x8 n0 = load_b(mn, pass, 0);
            f16x8 n1 = load_b(mn, pass, 1);
            acc[0] = __builtin_amdgcn_mfma_f32_32x32x16_f16(f.v, bC0, acc[0], 0, 0, 0);
            acc[1] = __builtin_amdgcn_mfma_f32_32x32x16_f16(f.v, bC1, acc[1], 0, 0, 0);
            bC0 = n0; bC1 = n1;
        }
    }

    // ---- epilogue: bias + ELU + nontemporal fp32 store ----
    #pragma unroll
    for (int c = 0; c < 2; ++c) {
        int col = ch * 64 + c * 32 + arow;
        #pragma unroll
        for (int v = 0; v < 16; ++v) {
            int lr = (v & 3) + 8 * (v >> 2) + 4 * q;   // local row 0..31 in M-tile
            int b  = mt * 2 + (lr >> 4);
            int p  = p0 + (lr & 15);
            float val = acc[c][v] + bias[(size_t)p * CO_ + col];
            val = (val > 0.f) ? val : (__expf(val) - 1.f);
            __builtin_nontemporal_store(val, &out[((size_t)b * P_ + p) * CO_ + col]);
        }
    }
}

extern "C" void kernel_launch(void* const* d_in, const int* in_sizes, int n_in,
                              void* d_out, int out_size, void* d_ws, size_t ws_size,
                              hipStream_t stream) {
    const float* in_pc   = (const float*)d_in[0];
    const float* raw_w   = (const float*)d_in[1];
    const float* weights = (const float*)d_in[2];
    const float* bias    = (const float*)d_in[3];
    const int*   nbr     = (const int*)  d_in[4];
    float* out = (float*)d_out;

    const size_t need = (size_t)WN_ * 8 * 128 * 8 * sizeof(ushort);   // 278,528 B
    if (d_ws != nullptr && ws_size >= need) {
        ushort* wsb = (ushort*)d_ws;
        prep_wm<<<dim3(WN_ * 1024 / 256), dim3(256), 0, stream>>>(weights, wsb);
        lasm_fused<true><<<dim3(NBLK), dim3(256), 0, stream>>>(
            in_pc, raw_w, weights, bias, nbr, wsb, out);
    } else {
        lasm_fused<false><<<dim3(NBLK), dim3(256), 0, stream>>>(
            in_pc, raw_w, weights, bias, nbr, nullptr, out);
    }
}

// Round 9
// 191.382 us; speedup vs baseline: 2.6147x; 2.6147x over previous
//
#include <hip/hip_runtime.h>
#include <stdint.h>

// Problem constants
#define B_   4
#define P_   20000
#define NB_  9
#define WN_  17
#define CI_  64
#define CO_  128
#define PTS  16            // points per block -> 64 rows = 2 M-tiles of 32
#define NBLK (P_ / PTS)    // 1250 blocks

#define WSB_BYTES   278528              // WN*2*4096 ushorts
#define XG_ELEMS    (B_ * P_ * CI_)     // 5,120,000 f16
#define XG_OFFSET   (WSB_BYTES / 2)     // ushort offset of xg in ws

typedef __fp16 f16x8 __attribute__((ext_vector_type(8)));
typedef __fp16 h2    __attribute__((ext_vector_type(2)));
typedef float  f32x16 __attribute__((ext_vector_type(16)));

union H2U { h2 h; uint32_t u; };
union F8U { f16x8 v; h2 h[4]; __fp16 e[8]; uint4 u; };

// wsb granule (16B = 8 f16): index (((m*2+pass)*4 + oloc)*128 + co)*8 ushorts.
// Consecutive co contiguous -> a wave's 32-lane fragment load is 512B dense.
__global__ void prep_wm(const float* __restrict__ w, ushort* __restrict__ wsb) {
    int i = blockIdx.x * 256 + threadIdx.x;     // 0 .. 17407 (17*2*4*128)
    int m2p  = i >> 9;                          // m*2+pass
    int r    = i & 511;
    int oloc = r >> 7, co = r & 127;
    int m = m2p >> 1, p = m2p & 1;
    const float* src = w + (size_t)m * (CO_ * CI_) + co * CI_ + (p * 4 + oloc) * 8;
    float4 v0 = *(const float4*)(src);
    float4 v1 = *(const float4*)(src + 4);
    F8U h;
    h.h[0] = __builtin_amdgcn_cvt_pkrtz(v0.x, v0.y);
    h.h[1] = __builtin_amdgcn_cvt_pkrtz(v0.z, v0.w);
    h.h[2] = __builtin_amdgcn_cvt_pkrtz(v1.x, v1.y);
    h.h[3] = __builtin_amdgcn_cvt_pkrtz(v1.z, v1.w);
    *(uint4*)&wsb[(size_t)((m2p * 4 + oloc) * 128 + co) * 8] = h.u;
}

// prep: in_pc fp32 -> f16 copy (same layout), 8 floats per thread
__global__ void prep_x(const float* __restrict__ in_pc, ushort* __restrict__ xg) {
    size_t i = (size_t)(blockIdx.x * 256 + threadIdx.x) * 8;   // 640,000 threads
    float4 v0 = *(const float4*)(in_pc + i);
    float4 v1 = *(const float4*)(in_pc + i + 4);
    F8U h;
    h.h[0] = __builtin_amdgcn_cvt_pkrtz(v0.x, v0.y);
    h.h[1] = __builtin_amdgcn_cvt_pkrtz(v0.z, v0.w);
    h.h[2] = __builtin_amdgcn_cvt_pkrtz(v1.x, v1.y);
    h.h[3] = __builtin_amdgcn_cvt_pkrtz(v1.z, v1.w);
    *(uint4*)&xg[i] = h.u;
}

template <bool PRE>
__global__ __launch_bounds__(256, 3)
void lasm_fused(const float* __restrict__ in_pc,    // (B,P,CI)    f32
                const float* __restrict__ raw_w,    // (P,NB,WN)   f32
                const float* __restrict__ weights,  // (WN,CO*CI)  f32
                const float* __restrict__ bias,     // (P,CO)      f32
                const int*   __restrict__ nbr,      // (P,NB)      int32
                const ushort* __restrict__ wsb,     // pre-swizzled f16 Wm panel
                const ushort* __restrict__ xg,      // f16 copy of in_pc
                float*       __restrict__ out)      // (B,P,CO)    f32
{
    __shared__ __align__(16) int      s_nid[PTS * NB_];      // 144 ints
    __shared__ __align__(16) uint32_t s_w2[WN_ * NB_ * 17];  // [(m*9+n)*17+pl]

    const int tid  = threadIdx.x;
    const int lane = tid & 63;
    const int wv   = tid >> 6;
    const int arow = lane & 31;       // row within M-tile / co within co-tile
    const int q    = lane >> 5;       // k-half
    const int mt   = wv >> 1;         // M-tile: rows mt*32 .. mt*32+31
    const int ch   = wv & 1;          // co half: cols ch*64 .. ch*64+63
    const int p0   = blockIdx.x * PTS;

    // ---- prologue staging (the ONLY barrier in the kernel) ----
    if (tid < PTS * NB_) s_nid[tid] = nbr[p0 * NB_ + tid];
    for (int idx = tid; idx < PTS * NB_ * WN_; idx += 256) {
        int pl2 = idx / (NB_ * WN_);
        int rem = idx % (NB_ * WN_);
        int n   = rem / WN_;
        int m   = rem % WN_;
        float wf = raw_w[(size_t)p0 * NB_ * WN_ + idx];
        H2U c; c.h = __builtin_amdgcn_cvt_pkrtz(wf, wf);
        s_w2[(m * NB_ + n) * 17 + pl2] = c.u;
    }
    __syncthreads();

    f32x16 acc[2];
    #pragma unroll
    for (int c = 0; c < 2; ++c)
        #pragma unroll
        for (int j = 0; j < 16; ++j) acc[c][j] = 0.f;

    const int brow = mt * 2 + (arow >> 4);    // batch of this lane's row
    const int pl   = arow & 15;               // point-local index
    const size_t binpc = (size_t)brow * P_ * CI_;

    // B-fragment load, direct global->VGPR (L2-resident panel, no LDS, no barrier)
    auto load_b = [&](int m, int pass, int kk, int c) -> f16x8 {
        int oloc = kk * 2 + q;
        if (PRE) {
            F8U r;
            r.u = *(const uint4*)&wsb[(size_t)(((m * 2 + pass) * 4 + oloc) * 128
                                               + ch * 64 + c * 32 + arow) * 8];
            return r.v;
        } else {
            const float* s = weights + (size_t)m * (CO_ * CI_)
                           + (ch * 64 + c * 32 + arow) * CI_ + (pass * 4 + oloc) * 8;
            float4 v0 = *(const float4*)(s);
            float4 v1 = *(const float4*)(s + 4);
            F8U r;
            r.h[0] = __builtin_amdgcn_cvt_pkrtz(v0.x, v0.y);
            r.h[1] = __builtin_amdgcn_cvt_pkrtz(v0.z, v0.w);
            r.h[2] = __builtin_amdgcn_cvt_pkrtz(v1.x, v1.y);
            r.h[3] = __builtin_amdgcn_cvt_pkrtz(v1.z, v1.w);
            return r.v;
        }
    };

    #pragma unroll 1
    for (int pass = 0; pass < 2; ++pass) {
        // ---- gather x: octs (pass*4+q) and (pass*4+2+q), f16 direct if PRE ----
        h2 x[NB_][8];
        #pragma unroll
        for (int n = 0; n < NB_; ++n) {
            uint32_t nid = (uint32_t)s_nid[pl * NB_ + n];
            if (nid < (uint32_t)P_) {
                if (PRE) {
                    const ushort* src = xg + binpc + (size_t)nid * CI_ + (pass * 4 + q) * 8;
                    F8U a; a.u = *(const uint4*)(src);        // oct pass*4+q
                    F8U b; b.u = *(const uint4*)(src + 16);   // oct pass*4+2+q
                    x[n][0] = a.h[0]; x[n][1] = a.h[1]; x[n][2] = a.h[2]; x[n][3] = a.h[3];
                    x[n][4] = b.h[0]; x[n][5] = b.h[1]; x[n][6] = b.h[2]; x[n][7] = b.h[3];
                } else {
                    const float* src = in_pc + binpc + (size_t)nid * CI_ + pass * 32 + q * 8;
                    float4 a0 = *(const float4*)(src);
                    float4 a1 = *(const float4*)(src + 4);
                    float4 b0 = *(const float4*)(src + 16);
                    float4 b1 = *(const float4*)(src + 20);
                    x[n][0] = __builtin_amdgcn_cvt_pkrtz(a0.x, a0.y);
                    x[n][1] = __builtin_amdgcn_cvt_pkrtz(a0.z, a0.w);
                    x[n][2] = __builtin_amdgcn_cvt_pkrtz(a1.x, a1.y);
                    x[n][3] = __builtin_amdgcn_cvt_pkrtz(a1.z, a1.w);
                    x[n][4] = __builtin_amdgcn_cvt_pkrtz(b0.x, b0.y);
                    x[n][5] = __builtin_amdgcn_cvt_pkrtz(b0.z, b0.w);
                    x[n][6] = __builtin_amdgcn_cvt_pkrtz(b1.x, b1.y);
                    x[n][7] = __builtin_amdgcn_cvt_pkrtz(b1.z, b1.w);
                }
            } else {
                h2 z = {(__fp16)0.f, (__fp16)0.f};
                #pragma unroll
                for (int j = 0; j < 8; ++j) x[n][j] = z;
            }
        }

        // ---- software-pipelined, barrier-free m-loop ----
        f16x8 bA0 = load_b(0, pass, 0, 0);
        f16x8 bA1 = load_b(0, pass, 0, 1);
        H2U wc[9];
        #pragma unroll
        for (int n = 0; n < NB_; ++n) wc[n].u = s_w2[n * 17 + pl];   // m=0

        for (int m = 0; m < WN_; ++m) {
            int mn = (m + 1 < WN_) ? m + 1 : m;       // clamped prefetch

            // prefetch next-m per-lane w (LDS latency covered by this iter's work)
            H2U wcn[9];
            #pragma unroll
            for (int n = 0; n < NB_; ++n) wcn[n].u = s_w2[(mn * NB_ + n) * 17 + pl];

            // kk=1 B fragments (in flight during stage-1)
            f16x8 bB0 = load_b(m, pass, 1, 0);
            f16x8 bB1 = load_b(m, pass, 1, 1);

            // stage-1 in registers: fuse[row=arow][this pass's 4 octs]
            F8U f[2];
            #pragma unroll
            for (int kk = 0; kk < 2; ++kk) {
                #pragma unroll
                for (int r4 = 0; r4 < 4; ++r4) {
                    h2 c = {(__fp16)0.f, (__fp16)0.f};
                    #pragma unroll
                    for (int n = 0; n < NB_; ++n) c += wc[n].h * x[n][kk * 4 + r4];
                    f[kk].h[r4] = c;
                }
            }

            acc[0] = __builtin_amdgcn_mfma_f32_32x32x16_f16(f[0].v, bA0, acc[0], 0, 0, 0);
            acc[1] = __builtin_amdgcn_mfma_f32_32x32x16_f16(f[0].v, bA1, acc[1], 0, 0, 0);

            f16x8 nA0 = load_b(mn, pass, 0, 0);
            f16x8 nA1 = load_b(mn, pass, 0, 1);
            acc[0] = __builtin_amdgcn_mfma_f32_32x32x16_f16(f[1].v, bB0, acc[0], 0, 0, 0);
            acc[1] = __builtin_amdgcn_mfma_f32_32x32x16_f16(f[1].v, bB1, acc[1], 0, 0, 0);

            bA0 = nA0; bA1 = nA1;
            #pragma unroll
            for (int n = 0; n < NB_; ++n) wc[n] = wcn[n];
        }
    }

    // ---- epilogue: bias + ELU + nontemporal fp32 store ----
    #pragma unroll
    for (int c = 0; c < 2; ++c) {
        int col = ch * 64 + c * 32 + arow;
        #pragma unroll
        for (int v = 0; v < 16; ++v) {
            int lr = (v & 3) + 8 * (v >> 2) + 4 * q;   // local row 0..31 in M-tile
            int b  = mt * 2 + (lr >> 4);
            int p  = p0 + (lr & 15);
            float val = acc[c][v] + bias[(size_t)p * CO_ + col];
            val = (val > 0.f) ? val : (__expf(val) - 1.f);
            __builtin_nontemporal_store(val, &out[((size_t)b * P_ + p) * CO_ + col]);
        }
    }
}

extern "C" void kernel_launch(void* const* d_in, const int* in_sizes, int n_in,
                              void* d_out, int out_size, void* d_ws, size_t ws_size,
                              hipStream_t stream) {
    const float* in_pc   = (const float*)d_in[0];
    const float* raw_w   = (const float*)d_in[1];
    const float* weights = (const float*)d_in[2];
    const float* bias    = (const float*)d_in[3];
    const int*   nbr     = (const int*)  d_in[4];
    float* out = (float*)d_out;

    const size_t need = WSB_BYTES + (size_t)XG_ELEMS * sizeof(ushort);  // ~10.5 MB
    if (d_ws != nullptr && ws_size >= need) {
        ushort* wsb = (ushort*)d_ws;
        ushort* xg  = (ushort*)d_ws + XG_OFFSET;
        prep_wm<<<dim3(WN_ * 1024 / 256), dim3(256), 0, stream>>>(weights, wsb);
        prep_x<<<dim3(XG_ELEMS / 8 / 256), dim3(256), 0, stream>>>(in_pc, xg);
        lasm_fused<true><<<dim3(NBLK), dim3(256), 0, stream>>>(
            in_pc, raw_w, weights, bias, nbr, wsb, xg, out);
    } else {
        lasm_fused<false><<<dim3(NBLK), dim3(256), 0, stream>>>(
            in_pc, raw_w, weights, bias, nbr, nullptr, nullptr, out);
    }
}